// Round 1
// baseline (51498.218 us; speedup 1.0000x reference)
//
#include <hip/hip_runtime.h>
#include <math.h>

namespace {

constexpr int kNL = 24, kD = 768, kDi = 1536, kN = 16, kR = 48, kK = 4, kV = 50280, kNH = 12;
constexpr int kB = 4, kS = 256;
constexpr int kMtok = kB * kS;   // 1024 token rows
constexpr int kMref = kB * kNL;  // 96 refine rows

__device__ __forceinline__ float siluf(float x) { return x / (1.f + expf(-x)); }

// ---------------- GEMM: C[M,N] = A[M,K] @ B[N,K]^T  (+bias, act, residual) ----
// ACT: 0 none, 1 softplus, 2 gelu(exact)
template <int BIAS, int ACT, int RES>
__global__ __launch_bounds__(256) void gemm_kernel(
    const float* __restrict__ A, int lda,
    const float* __restrict__ B, int ldb,
    float* __restrict__ C, int ldc,
    const float* __restrict__ bias,
    int M, int N, int K)
{
    __shared__ float As[16][68];
    __shared__ float Bs[16][68];
    const int tid = threadIdx.x;
    const int m0 = blockIdx.y * 64;
    const int n0 = blockIdx.x * 64;
    const int tx = tid & 15;
    const int ty = tid >> 4;
    float acc[4][4] = {};

    for (int k0 = 0; k0 < K; k0 += 16) {
#pragma unroll
        for (int i = 0; i < 4; ++i) {
            int idx = tid + i * 256;
            int mm = idx >> 4;
            int kk = idx & 15;
            int gm = m0 + mm;
            int gn = n0 + mm;
            As[kk][mm] = (gm < M) ? A[(size_t)gm * lda + (k0 + kk)] : 0.f;
            Bs[kk][mm] = (gn < N) ? B[(size_t)gn * ldb + (k0 + kk)] : 0.f;
        }
        __syncthreads();
#pragma unroll
        for (int k = 0; k < 16; ++k) {
            float4 av = *(const float4*)&As[k][ty * 4];
            float4 bv = *(const float4*)&Bs[k][tx * 4];
            float a[4] = {av.x, av.y, av.z, av.w};
            float bq[4] = {bv.x, bv.y, bv.z, bv.w};
#pragma unroll
            for (int i = 0; i < 4; ++i)
#pragma unroll
                for (int j = 0; j < 4; ++j)
                    acc[i][j] = fmaf(a[i], bq[j], acc[i][j]);
        }
        __syncthreads();
    }

#pragma unroll
    for (int i = 0; i < 4; ++i) {
        int gm = m0 + ty * 4 + i;
        if (gm >= M) continue;
#pragma unroll
        for (int j = 0; j < 4; ++j) {
            int gn = n0 + tx * 4 + j;
            if (gn >= N) continue;
            float v = acc[i][j];
            if (BIAS) v += bias[gn];
            if (ACT == 1) v = fmaxf(v, 0.f) + log1pf(expf(-fabsf(v)));           // softplus (stable)
            if (ACT == 2) v = 0.5f * v * (1.f + erff(v * 0.70710678118654752f)); // exact gelu
            size_t ci = (size_t)gm * ldc + gn;
            if (RES) v += C[ci];
            C[ci] = v;
        }
    }
}

template <int BIAS, int ACT, int RES>
static void gemm(const float* A, int lda, const float* B, int ldb, float* C, int ldc,
                 const float* bias, int M, int N, int K, hipStream_t s)
{
    dim3 g((N + 63) / 64, (M + 63) / 64);
    gemm_kernel<BIAS, ACT, RES><<<g, dim3(256), 0, s>>>(A, lda, B, ldb, C, ldc, bias, M, N, K);
}

// ---------------- embedding ----------------
__global__ void embed_kernel(const int* __restrict__ ids, const int* __restrict__ msk,
                             const float* __restrict__ embed, float* __restrict__ h)
{
    int i = blockIdx.x * 256 + threadIdx.x;      // kMtok * kD threads exactly
    int row = i / kD, col = i - row * kD;
    h[i] = embed[(size_t)ids[row] * kD + col] * (float)msk[row];
}

// ---------------- RMSNorm (width 768) ----------------
__global__ __launch_bounds__(256) void rms_kernel(const float* __restrict__ x,
                                                  const float* __restrict__ w,
                                                  float* __restrict__ out)
{
    __shared__ float red[256];
    int row = blockIdx.x;
    int tid = threadIdx.x;
    const float* xr = x + (size_t)row * kD;
    float s = 0.f;
    for (int j = tid; j < kD; j += 256) { float v = xr[j]; s += v * v; }
    red[tid] = s;
    __syncthreads();
    for (int o = 128; o > 0; o >>= 1) { if (tid < o) red[tid] += red[tid + o]; __syncthreads(); }
    float rs = rsqrtf(red[0] / (float)kD + 1e-5f);
    for (int j = tid; j < kD; j += 256) out[(size_t)row * kD + j] = xr[j] * rs * w[j];
}

// ---------------- LayerNorm (width 768) ----------------
__global__ __launch_bounds__(256) void ln_kernel(const float* __restrict__ x,
                                                 const float* __restrict__ w,
                                                 const float* __restrict__ b,
                                                 float* __restrict__ out)
{
    __shared__ float r1[256], r2[256];
    int row = blockIdx.x;
    int tid = threadIdx.x;
    const float* xr = x + (size_t)row * kD;
    float s = 0.f, s2 = 0.f;
    for (int j = tid; j < kD; j += 256) { float v = xr[j]; s += v; s2 += v * v; }
    r1[tid] = s; r2[tid] = s2;
    __syncthreads();
    for (int o = 128; o > 0; o >>= 1) {
        if (tid < o) { r1[tid] += r1[tid + o]; r2[tid] += r2[tid + o]; }
        __syncthreads();
    }
    float mean = r1[0] / (float)kD;
    float var = r2[0] / (float)kD - mean * mean;
    float rs = rsqrtf(var + 1e-5f);
    for (int j = tid; j < kD; j += 256)
        out[(size_t)row * kD + j] = (xr[j] - mean) * rs * w[j] + b[j];
}

// ---------------- causal conv (K=4) + bias + silu;  x = xz[:, :Di] ----------
__global__ void conv_kernel(const float* __restrict__ xz, const float* __restrict__ cw,
                            const float* __restrict__ cb, float* __restrict__ xc)
{
    int i = blockIdx.x * 256 + threadIdx.x;      // kMtok * kDi threads exactly
    int bt = i / kDi, d = i - bt * kDi;
    int b = bt / kS, t = bt - b * kS;
    float s = cb[d];
#pragma unroll
    for (int k = 0; k < kK; ++k) {
        int tt = t - (kK - 1) + k;
        if (tt >= 0) s += xz[(size_t)(b * kS + tt) * (2 * kDi) + d] * cw[d * kK + k];
    }
    xc[i] = siluf(s);
}

// ---------------- selective scan + gating --------------------------------
// thread = (b, d, n); 16 n-lanes per group; y[b,t,d] = (sum_n hs*C + x*Dp) * silu(z)
__global__ __launch_bounds__(256) void scan_kernel(
    const float* __restrict__ dlt, const float* __restrict__ xc,
    const float* __restrict__ xz, const float* __restrict__ dbl,
    const float* __restrict__ alog, const float* __restrict__ dp,
    float* __restrict__ states, float* __restrict__ y)
{
    int gid = blockIdx.x * 256 + threadIdx.x;    // kB*kDi*kN threads
    int n = gid & 15;
    int d = (gid >> 4) % kDi;
    int b = gid / (kDi * kN);
    float Areg = -expf(alog[d * kN + n]);
    float dpv = dp[d];
    size_t sidx = (size_t)(b * kDi + d) * kN + n;
    float hs = states[sidx];
    for (int t = 0; t < kS; ++t) {
        int bt = b * kS + t;
        float dv = dlt[(size_t)bt * kDi + d];
        float xv = xc[(size_t)bt * kDi + d];
        float Bv = dbl[(size_t)bt * 80 + kR + n];
        float Cv = dbl[(size_t)bt * 80 + kR + kN + n];
        hs = expf(dv * Areg) * hs + (dv * xv) * Bv;
        float p = hs * Cv;
        p += __shfl_xor(p, 1, 16);
        p += __shfl_xor(p, 2, 16);
        p += __shfl_xor(p, 4, 16);
        p += __shfl_xor(p, 8, 16);
        if (n == 0) {
            float zv = xz[(size_t)bt * (2 * kDi) + kDi + d];
            y[(size_t)bt * kDi + d] = (p + xv * dpv) * siluf(zv);
        }
    }
    states[sidx] = hs;
}

// ---------------- refine: d = states . C_w  -> (b*24+s, di) ----------------
__global__ void contract_kernel(const float* __restrict__ st, const float* __restrict__ Cw,
                                float* __restrict__ dDi)
{
    int i = blockIdx.x * 256 + threadIdx.x;      // kMref * kDi exactly
    int row = i / kDi, di = i - row * kDi;       // row = b*24 + s
    int b = row / kNL, s = row - b * kNL;
    const float* sp = st + ((size_t)(s * kB + b) * kDi + di) * kN;
    float acc = 0.f;
#pragma unroll
    for (int n = 0; n < kN; ++n) acc += sp[n] * Cw[n];
    dDi[i] = acc;
}

// ---------------- refine: states += d1536 * B_w --------------------------
__global__ void update_kernel(const float* __restrict__ d1536, const float* __restrict__ Bw,
                              float* __restrict__ st)
{
    int i = blockIdx.x * 256 + threadIdx.x;      // kMref * kDi exactly
    int row = i / kDi, di = i - row * kDi;
    int b = row / kNL, s = row - b * kNL;
    float dv = d1536[i];
    float* sp = st + ((size_t)(s * kB + b) * kDi + di) * kN;
#pragma unroll
    for (int n = 0; n < kN; ++n) sp[n] += dv * Bw[n];
}

// ---------------- tiny attention (B=4, S=24, 12 heads, hd=64) -------------
__global__ __launch_bounds__(32) void attn_kernel(const float* __restrict__ qkv,
                                                  float* __restrict__ o)
{
    int b = blockIdx.x / kNH;
    int hh = blockIdx.x - b * kNH;
    int sq = threadIdx.x;
    if (sq >= kNL) return;
    const float* qrow = qkv + (size_t)(b * kNL + sq) * (3 * kD) + hh * 64;
    float q[64];
#pragma unroll
    for (int e = 0; e < 64; ++e) q[e] = qrow[e];
    float sc[kNL];
    float mx = -1e30f;
    for (int sk = 0; sk < kNL; ++sk) {
        const float* krow = qkv + (size_t)(b * kNL + sk) * (3 * kD) + kD + hh * 64;
        float dt = 0.f;
#pragma unroll
        for (int e = 0; e < 64; ++e) dt += q[e] * krow[e];
        dt *= 0.125f;
        sc[sk] = dt;
        mx = fmaxf(mx, dt);
    }
    float sum = 0.f;
    for (int sk = 0; sk < kNL; ++sk) { sc[sk] = expf(sc[sk] - mx); sum += sc[sk]; }
    float inv = 1.f / sum;
    float out[64];
#pragma unroll
    for (int e = 0; e < 64; ++e) out[e] = 0.f;
    for (int sk = 0; sk < kNL; ++sk) {
        float wgt = sc[sk] * inv;
        const float* vrow = qkv + (size_t)(b * kNL + sk) * (3 * kD) + 2 * kD + hh * 64;
#pragma unroll
        for (int e = 0; e < 64; ++e) out[e] += wgt * vrow[e];
    }
    float* orow = o + (size_t)(b * kNL + sq) * kD + hh * 64;
#pragma unroll
    for (int e = 0; e < 64; ++e) orow[e] = out[e];
}

} // namespace

extern "C" void kernel_launch(void* const* d_in, const int* in_sizes, int n_in,
                              void* d_out, int out_size, void* d_ws, size_t ws_size,
                              hipStream_t stream)
{
    const int*   q_ids  = (const int*)d_in[0];
    const int*   q_msk  = (const int*)d_in[1];
    const int*   a_ids  = (const int*)d_in[2];
    const int*   a_msk  = (const int*)d_in[3];
    const float* embed  = (const float*)d_in[4];
    const float* norm_w = (const float*)d_in[5];
    const float* ipw    = (const float*)d_in[6];
    const float* cw     = (const float*)d_in[7];
    const float* cb     = (const float*)d_in[8];
    const float* xpw    = (const float*)d_in[9];
    const float* dpw    = (const float*)d_in[10];
    const float* dpb    = (const float*)d_in[11];
    const float* alog   = (const float*)d_in[12];
    const float* dpp    = (const float*)d_in[13];
    const float* opw    = (const float*)d_in[14];
    const float* norm_f = (const float*)d_in[15];
    const float* ln1w   = (const float*)d_in[16];
    const float* ln1b   = (const float*)d_in[17];
    const float* qkvw   = (const float*)d_in[18];
    const float* qkvbi  = (const float*)d_in[19];
    const float* aow    = (const float*)d_in[20];
    const float* aob    = (const float*)d_in[21];
    const float* ln2w   = (const float*)d_in[22];
    const float* ln2b   = (const float*)d_in[23];
    const float* ff1w   = (const float*)d_in[24];
    const float* ff1b   = (const float*)d_in[25];
    const float* ff2w   = (const float*)d_in[26];
    const float* ff2b   = (const float*)d_in[27];
    const float* Cwp    = (const float*)d_in[28];
    const float* powp   = (const float*)d_in[29];
    const float* Bwp    = (const float*)d_in[30];
    const float* piwp   = (const float*)d_in[31];

    float* wsp = (float*)d_ws;
    auto alloc = [&](size_t nfl) { float* p = wsp; wsp += nfl; return p; };
    float* h     = alloc((size_t)kMtok * kD);
    float* xin   = alloc((size_t)kMtok * kD);
    float* xz    = alloc((size_t)kMtok * 2 * kDi);
    float* xc    = alloc((size_t)kMtok * kDi);
    float* dblb  = alloc((size_t)kMtok * 80);
    float* dlt   = alloc((size_t)kMtok * kDi);
    float* yb    = alloc((size_t)kMtok * kDi);
    float* st    = alloc((size_t)kNL * kB * kDi * kN);
    float* dDi   = alloc((size_t)kMref * kDi);
    float* x768  = alloc((size_t)kMref * kD);
    float* tb    = alloc((size_t)kMref * kD);
    float* qkvB  = alloc((size_t)kMref * 3 * kD);
    float* o768  = alloc((size_t)kMref * kD);
    float* f3072 = alloc((size_t)kMref * 4 * kD);
    float* d1536 = alloc((size_t)kMref * kDi);

    hipMemsetAsync(st, 0, sizeof(float) * (size_t)kNL * kB * kDi * kN, stream);

    for (int pass = 0; pass < 2; ++pass) {
        const int* ids = pass ? a_ids : q_ids;
        const int* msk = pass ? a_msk : q_msk;

        embed_kernel<<<dim3(kMtok * kD / 256), dim3(256), 0, stream>>>(ids, msk, embed, h);

        for (int l = 0; l < kNL; ++l) {
            rms_kernel<<<dim3(kMtok), dim3(256), 0, stream>>>(h, norm_w + (size_t)l * kD, xin);
            gemm<0, 0, 0>(xin, kD, ipw + (size_t)l * 2 * kDi * kD, kD, xz, 2 * kDi,
                          nullptr, kMtok, 2 * kDi, kD, stream);
            conv_kernel<<<dim3(kMtok * kDi / 256), dim3(256), 0, stream>>>(
                xz, cw + (size_t)l * kDi * kK, cb + (size_t)l * kDi, xc);
            gemm<0, 0, 0>(xc, kDi, xpw + (size_t)l * 80 * kDi, kDi, dblb, 80,
                          nullptr, kMtok, 80, kDi, stream);
            gemm<1, 1, 0>(dblb, 80, dpw + (size_t)l * kDi * kR, kR, dlt, kDi,
                          dpb + (size_t)l * kDi, kMtok, kDi, kR, stream);
            scan_kernel<<<dim3(kB * kDi * kN / 256), dim3(256), 0, stream>>>(
                dlt, xc, xz, dblb, alog + (size_t)l * kDi * kN, dpp + (size_t)l * kDi,
                st + (size_t)l * kB * kDi * kN, yb);
            gemm<0, 0, 1>(yb, kDi, opw + (size_t)l * kD * kDi, kDi, h, kD,
                          nullptr, kMtok, kD, kDi, stream);
        }

        if (pass == 0) {
            for (int it = 0; it < 12; ++it) {
                contract_kernel<<<dim3(kMref * kDi / 256), dim3(256), 0, stream>>>(st, Cwp, dDi);
                gemm<0, 0, 0>(dDi, kDi, powp, kDi, x768, kD, nullptr, kMref, kD, kDi, stream);
                ln_kernel<<<dim3(kMref), dim3(256), 0, stream>>>(x768, ln1w, ln1b, tb);
                gemm<1, 0, 0>(tb, kD, qkvw, kD, qkvB, 3 * kD, qkvbi, kMref, 3 * kD, kD, stream);
                attn_kernel<<<dim3(kB * kNH), dim3(32), 0, stream>>>(qkvB, o768);
                gemm<1, 0, 1>(o768, kD, aow, kD, x768, kD, aob, kMref, kD, kD, stream);
                ln_kernel<<<dim3(kMref), dim3(256), 0, stream>>>(x768, ln2w, ln2b, tb);
                gemm<1, 2, 0>(tb, kD, ff1w, kD, f3072, 4 * kD, ff1b, kMref, 4 * kD, kD, stream);
                gemm<1, 0, 1>(f3072, 4 * kD, ff2w, 4 * kD, x768, kD, ff2b, kMref, kD, 4 * kD, stream);
                gemm<0, 0, 0>(x768, kD, piwp, kD, d1536, kDi, nullptr, kMref, kDi, kD, stream);
                update_kernel<<<dim3(kMref * kDi / 256), dim3(256), 0, stream>>>(d1536, Bwp, st);
            }
        } else {
            rms_kernel<<<dim3(kMtok), dim3(256), 0, stream>>>(h, norm_f, xin);
            gemm<0, 0, 0>(xin, kD, embed, kD, (float*)d_out, kV, nullptr, kMtok, kV, kD, stream);
        }
    }
}

// Round 2
// 21608.855 us; speedup vs baseline: 2.3832x; 2.3832x over previous
//
#include <hip/hip_runtime.h>
#include <math.h>

namespace {

constexpr int kNL = 24, kD = 768, kDi = 1536, kN = 16, kR = 48, kK = 4, kV = 50280, kNH = 12;
constexpr int kB = 4, kS = 256;
constexpr int kMtok = kB * kS;   // 1024 token rows
constexpr int kMref = kB * kNL;  // 96 refine rows
constexpr int kVp = 50304;       // kV padded to 128

using bf16x8 = __attribute__((ext_vector_type(8))) short;
using f32x4  = __attribute__((ext_vector_type(4))) float;

__device__ __forceinline__ float siluf(float x) { return x / (1.f + expf(-x)); }

__device__ __forceinline__ ushort f2b(float f) {
    union { float f; unsigned u; } v; v.f = f;
    unsigned u = v.u;
    unsigned r = (u + 0x7FFFu + ((u >> 16) & 1u)) >> 16;
    return (ushort)r;
}

#define GLOAD_LDS(g, l) \
    __builtin_amdgcn_global_load_lds((const __attribute__((address_space(1))) void*)(g), \
                                     (__attribute__((address_space(3))) void*)(l), 16, 0, 0)

// ---------------- bf16 MFMA GEMM: C[M,N] = A[M,K] @ B[N,K]^T ----------------
// A: bf16 [>=ceil128(M)][lda], B: bf16 [>=ceil128(N)][ldb], K multiple of 32.
// ACT: 0 none, 1 softplus, 2 gelu(exact). OUTMODE: 0 fp32, 1 fp32+bf16, 2 bf16 only.
template <int BIAS, int ACT, int RES, int OUTMODE>
__global__ __launch_bounds__(256) void gemm_bf16(
    const ushort* __restrict__ A, int lda,
    const ushort* __restrict__ B, int ldb,
    float* __restrict__ C, int ldc,
    ushort* __restrict__ Cbf, int ldcb,
    const float* __restrict__ bias,
    int M, int N, int K)
{
    __shared__ ushort As[128 * 32];
    __shared__ ushort Bs[128 * 32];
    const int tid  = threadIdx.x;
    const int lane = tid & 63;
    const int wave = tid >> 6;
    const int m0 = blockIdx.y * 128;
    const int n0 = blockIdx.x * 128;
    const int wr = (wave >> 1) * 64;
    const int wc = (wave & 1) * 64;

    f32x4 acc[4][4];
#pragma unroll
    for (int i = 0; i < 4; ++i)
#pragma unroll
        for (int j = 0; j < 4; ++j) acc[i][j] = f32x4{0.f, 0.f, 0.f, 0.f};

    // staging: thread -> (row = tid>>2, col8 = (tid&3)*8); wave w covers rows 16w..16w+15
    const int srow = tid >> 2;
    const int scol = (tid & 3) * 8;
    const ushort* ga = A + (size_t)(m0 + srow) * lda + scol;
    const ushort* gb = B + (size_t)(n0 + srow) * ldb + scol;
    const size_t astep = 64 * (size_t)lda;
    const size_t bstep = 64 * (size_t)ldb;
    ushort* lA0 = As + wave * 512;
    ushort* lA1 = As + 2048 + wave * 512;
    ushort* lB0 = Bs + wave * 512;
    ushort* lB1 = Bs + 2048 + wave * 512;

    const int frow = lane & 15;        // fragment row/col within 16
    const int fk   = (lane >> 4) * 8;  // k-chunk

    for (int k0 = 0; k0 < K; k0 += 32) {
        GLOAD_LDS(ga, lA0);
        GLOAD_LDS(ga + astep, lA1);
        GLOAD_LDS(gb, lB0);
        GLOAD_LDS(gb + bstep, lB1);
        ga += 32; gb += 32;
        __syncthreads();
        bf16x8 fa[4], fb[4];
#pragma unroll
        for (int i = 0; i < 4; ++i) {
            fa[i] = *(const bf16x8*)&As[(wr + i * 16 + frow) * 32 + fk];
            fb[i] = *(const bf16x8*)&Bs[(wc + i * 16 + frow) * 32 + fk];
        }
#pragma unroll
        for (int i = 0; i < 4; ++i)
#pragma unroll
            for (int j = 0; j < 4; ++j)
                acc[i][j] = __builtin_amdgcn_mfma_f32_16x16x32_bf16(fa[i], fb[j], acc[i][j], 0, 0, 0);
        __syncthreads();
    }

    // epilogue: C/D layout col = lane&15, row = (lane>>4)*4 + q  [m89-verified]
    const int ccol = lane & 15;
    const int crow = (lane >> 4) * 4;
#pragma unroll
    for (int i = 0; i < 4; ++i) {
#pragma unroll
        for (int j = 0; j < 4; ++j) {
            int gn = n0 + wc + j * 16 + ccol;
            if (gn >= N) continue;
            float bv = BIAS ? bias[gn] : 0.f;
#pragma unroll
            for (int q = 0; q < 4; ++q) {
                int gm = m0 + wr + i * 16 + crow + q;
                if (gm >= M) continue;
                float v = acc[i][j][q] + bv;
                if (ACT == 1) v = fmaxf(v, 0.f) + log1pf(expf(-fabsf(v)));
                if (ACT == 2) v = 0.5f * v * (1.f + erff(v * 0.70710678118654752f));
                size_t ci = (size_t)gm * ldc + gn;
                if (RES) v += C[ci];
                if (OUTMODE != 2) C[ci] = v;
                if (OUTMODE >= 1) Cbf[(size_t)gm * ldcb + gn] = f2b(v);
            }
        }
    }
}

template <int BIAS, int ACT, int RES, int OUTMODE>
static void gemm(const ushort* A, int lda, const ushort* B, int ldb,
                 float* C, int ldc, ushort* Cb, int ldcb,
                 const float* bias, int M, int N, int K, hipStream_t s)
{
    dim3 g((N + 127) / 128, (M + 127) / 128);
    gemm_bf16<BIAS, ACT, RES, OUTMODE><<<g, dim3(256), 0, s>>>(A, lda, B, ldb, C, ldc, Cb, ldcb, bias, M, N, K);
}

// ---------------- conversions ----------------
__global__ void cvt_kernel(const float* __restrict__ src, ushort* __restrict__ dst, int n) {
    int i = (blockIdx.x * 256 + threadIdx.x) * 4;
    if (i >= n) return;
    float4 v = *(const float4*)(src + i);
    ushort4 o; o.x = f2b(v.x); o.y = f2b(v.y); o.z = f2b(v.z); o.w = f2b(v.w);
    *(ushort4*)(dst + i) = o;
}

// xpw [24][80][1536] -> padded [24][128][1536]
__global__ void cvt_xpw_kernel(const float* __restrict__ src, ushort* __restrict__ dst) {
    int i = (blockIdx.x * 256 + threadIdx.x) * 4;
    if (i >= 24 * 80 * 1536) return;
    int l = i / (80 * 1536), r = i - l * (80 * 1536);
    int row = r / 1536, col = r - row * 1536;
    float4 v = *(const float4*)(src + i);
    ushort4 o; o.x = f2b(v.x); o.y = f2b(v.y); o.z = f2b(v.z); o.w = f2b(v.w);
    *(ushort4*)(dst + ((size_t)(l * 128 + row)) * 1536 + col) = o;
}

// dpw [24][1536][48] -> padded [24][1536][64] (K-pad MUST be zero)
__global__ void cvt_dpw_kernel(const float* __restrict__ src, ushort* __restrict__ dst) {
    int i = blockIdx.x * 256 + threadIdx.x;
    if (i >= 24 * 1536 * 64) return;
    int col = i & 63, row = i >> 6;
    dst[i] = (col < 48) ? f2b(src[(size_t)row * 48 + col]) : (ushort)0;
}

// dblb cols 0..47 -> dt input [1024][64], K-pad zero
__global__ void dtpad_kernel(const float* __restrict__ dblb, ushort* __restrict__ dtin) {
    int i = blockIdx.x * 256 + threadIdx.x;   // 1024*64
    int col = i & 63, row = i >> 6;
    dtin[i] = (col < 48) ? f2b(dblb[(size_t)row * 128 + col]) : (ushort)0;
}

// ---------------- embedding ----------------
__global__ void embed_kernel(const int* __restrict__ ids, const int* __restrict__ msk,
                             const float* __restrict__ embed, float* __restrict__ h)
{
    int i = blockIdx.x * 256 + threadIdx.x;
    int row = i / kD, col = i - row * kD;
    h[i] = embed[(size_t)ids[row] * kD + col] * (float)msk[row];
}

// ---------------- RMSNorm -> bf16 ----------------
__global__ __launch_bounds__(256) void rms_kernel(const float* __restrict__ x,
                                                  const float* __restrict__ w,
                                                  ushort* __restrict__ out)
{
    __shared__ float red[256];
    int row = blockIdx.x, tid = threadIdx.x;
    const float* xr = x + (size_t)row * kD;
    float s = 0.f;
    for (int j = tid; j < kD; j += 256) { float v = xr[j]; s += v * v; }
    red[tid] = s; __syncthreads();
    for (int o = 128; o > 0; o >>= 1) { if (tid < o) red[tid] += red[tid + o]; __syncthreads(); }
    float rs = rsqrtf(red[0] / (float)kD + 1e-5f);
    for (int j = tid; j < kD; j += 256) out[(size_t)row * kD + j] = f2b(xr[j] * rs * w[j]);
}

// ---------------- LayerNorm -> bf16 ----------------
__global__ __launch_bounds__(256) void ln_kernel(const float* __restrict__ x,
                                                 const float* __restrict__ w,
                                                 const float* __restrict__ b,
                                                 ushort* __restrict__ out)
{
    __shared__ float r1[256], r2[256];
    int row = blockIdx.x, tid = threadIdx.x;
    const float* xr = x + (size_t)row * kD;
    float s = 0.f, s2 = 0.f;
    for (int j = tid; j < kD; j += 256) { float v = xr[j]; s += v; s2 += v * v; }
    r1[tid] = s; r2[tid] = s2; __syncthreads();
    for (int o = 128; o > 0; o >>= 1) {
        if (tid < o) { r1[tid] += r1[tid + o]; r2[tid] += r2[tid + o]; }
        __syncthreads();
    }
    float mean = r1[0] / (float)kD;
    float var = r2[0] / (float)kD - mean * mean;
    float rs = rsqrtf(var + 1e-5f);
    for (int j = tid; j < kD; j += 256)
        out[(size_t)row * kD + j] = f2b((xr[j] - mean) * rs * w[j] + b[j]);
}

// ---------------- causal conv (K=4) + bias + silu ----------
__global__ void conv_kernel(const float* __restrict__ xz, const float* __restrict__ cw,
                            const float* __restrict__ cb, float* __restrict__ xc,
                            ushort* __restrict__ xc_bf)
{
    int i = blockIdx.x * 256 + threadIdx.x;   // kMtok * kDi
    int bt = i / kDi, d = i - bt * kDi;
    int b = bt / kS, t = bt - b * kS;
    float s = cb[d];
#pragma unroll
    for (int k = 0; k < kK; ++k) {
        int tt = t - (kK - 1) + k;
        if (tt >= 0) s += xz[(size_t)(b * kS + tt) * (2 * kDi) + d] * cw[d * kK + k];
    }
    float v = siluf(s);
    xc[i] = v;
    xc_bf[i] = f2b(v);
}

// ---------------- selective scan + gating (y -> bf16) ---------------------
__global__ __launch_bounds__(256) void scan_kernel(
    const float* __restrict__ dlt, const float* __restrict__ xc,
    const float* __restrict__ xz, const float* __restrict__ dbl,
    const float* __restrict__ alog, const float* __restrict__ dp,
    float* __restrict__ states, ushort* __restrict__ y)
{
    int gid = blockIdx.x * 256 + threadIdx.x;    // kB*kDi*kN threads
    int n = gid & 15;
    int d = (gid >> 4) % kDi;
    int b = gid / (kDi * kN);
    float Areg = -expf(alog[d * kN + n]);
    float dpv = dp[d];
    size_t sidx = (size_t)(b * kDi + d) * kN + n;
    float hs = states[sidx];
    for (int t = 0; t < kS; ++t) {
        int bt = b * kS + t;
        float dv = dlt[(size_t)bt * kDi + d];
        float xv = xc[(size_t)bt * kDi + d];
        float Bv = dbl[(size_t)bt * 128 + kR + n];
        float Cv = dbl[(size_t)bt * 128 + kR + kN + n];
        hs = expf(dv * Areg) * hs + (dv * xv) * Bv;
        float p = hs * Cv;
        p += __shfl_xor(p, 1, 16);
        p += __shfl_xor(p, 2, 16);
        p += __shfl_xor(p, 4, 16);
        p += __shfl_xor(p, 8, 16);
        if (n == 0) {
            float zv = xz[(size_t)bt * (2 * kDi) + kDi + d];
            y[(size_t)bt * kDi + d] = f2b((p + xv * dpv) * siluf(zv));
        }
    }
    states[sidx] = hs;
}

// ---------------- refine: d = states . C_w -> bf16 [row, di] --------------
__global__ void contract_kernel(const float* __restrict__ st, const float* __restrict__ Cw,
                                ushort* __restrict__ dDi)
{
    int i = blockIdx.x * 256 + threadIdx.x;      // kMref * kDi
    int row = i / kDi, di = i - row * kDi;
    int b = row / kNL, s = row - b * kNL;
    const float* sp = st + ((size_t)(s * kB + b) * kDi + di) * kN;
    float acc = 0.f;
#pragma unroll
    for (int n = 0; n < kN; ++n) acc += sp[n] * Cw[n];
    dDi[i] = f2b(acc);
}

// ---------------- refine: states += d1536 * B_w --------------------------
__global__ void update_kernel(const float* __restrict__ d1536, const float* __restrict__ Bw,
                              float* __restrict__ st)
{
    int i = blockIdx.x * 256 + threadIdx.x;      // kMref * kDi
    int row = i / kDi, di = i - row * kDi;
    int b = row / kNL, s = row - b * kNL;
    float dv = d1536[i];
    float* sp = st + ((size_t)(s * kB + b) * kDi + di) * kN;
#pragma unroll
    for (int n = 0; n < kN; ++n) sp[n] += dv * Bw[n];
}

// ---------------- tiny attention (B=4, S=24, 12 heads, hd=64) -> bf16 -----
__global__ __launch_bounds__(32) void attn_kernel(const float* __restrict__ qkv,
                                                  ushort* __restrict__ o)
{
    int b = blockIdx.x / kNH;
    int hh = blockIdx.x - b * kNH;
    int sq = threadIdx.x;
    if (sq >= kNL) return;
    const float* qrow = qkv + (size_t)(b * kNL + sq) * (3 * kD) + hh * 64;
    float q[64];
#pragma unroll
    for (int e = 0; e < 64; ++e) q[e] = qrow[e];
    float sc[kNL];
    float mx = -1e30f;
    for (int sk = 0; sk < kNL; ++sk) {
        const float* krow = qkv + (size_t)(b * kNL + sk) * (3 * kD) + kD + hh * 64;
        float dt = 0.f;
#pragma unroll
        for (int e = 0; e < 64; ++e) dt += q[e] * krow[e];
        dt *= 0.125f;
        sc[sk] = dt;
        mx = fmaxf(mx, dt);
    }
    float sum = 0.f;
    for (int sk = 0; sk < kNL; ++sk) { sc[sk] = expf(sc[sk] - mx); sum += sc[sk]; }
    float inv = 1.f / sum;
    float out[64];
#pragma unroll
    for (int e = 0; e < 64; ++e) out[e] = 0.f;
    for (int sk = 0; sk < kNL; ++sk) {
        float wgt = sc[sk] * inv;
        const float* vrow = qkv + (size_t)(b * kNL + sk) * (3 * kD) + 2 * kD + hh * 64;
#pragma unroll
        for (int e = 0; e < 64; ++e) out[e] += wgt * vrow[e];
    }
    ushort* orow = o + (size_t)(b * kNL + sq) * kD + hh * 64;
#pragma unroll
    for (int e = 0; e < 64; ++e) orow[e] = f2b(out[e]);
}

} // namespace

extern "C" void kernel_launch(void* const* d_in, const int* in_sizes, int n_in,
                              void* d_out, int out_size, void* d_ws, size_t ws_size,
                              hipStream_t stream)
{
    const int*   q_ids  = (const int*)d_in[0];
    const int*   q_msk  = (const int*)d_in[1];
    const int*   a_ids  = (const int*)d_in[2];
    const int*   a_msk  = (const int*)d_in[3];
    const float* embed  = (const float*)d_in[4];
    const float* norm_w = (const float*)d_in[5];
    const float* ipw    = (const float*)d_in[6];
    const float* cw     = (const float*)d_in[7];
    const float* cb     = (const float*)d_in[8];
    const float* xpw    = (const float*)d_in[9];
    const float* dpw    = (const float*)d_in[10];
    const float* dpb    = (const float*)d_in[11];
    const float* alog   = (const float*)d_in[12];
    const float* dpp    = (const float*)d_in[13];
    const float* opw    = (const float*)d_in[14];
    const float* norm_f = (const float*)d_in[15];
    const float* ln1w   = (const float*)d_in[16];
    const float* ln1b   = (const float*)d_in[17];
    const float* qkvw   = (const float*)d_in[18];
    const float* qkvbi  = (const float*)d_in[19];
    const float* aow    = (const float*)d_in[20];
    const float* aob    = (const float*)d_in[21];
    const float* ln2w   = (const float*)d_in[22];
    const float* ln2b   = (const float*)d_in[23];
    const float* ff1w   = (const float*)d_in[24];
    const float* ff1b   = (const float*)d_in[25];
    const float* ff2w   = (const float*)d_in[26];
    const float* ff2b   = (const float*)d_in[27];
    const float* Cwp    = (const float*)d_in[28];
    const float* powp   = (const float*)d_in[29];
    const float* Bwp    = (const float*)d_in[30];
    const float* piwp   = (const float*)d_in[31];

    // ---- workspace arena (byte cursor, 256B aligned) ----
    char* base = (char*)d_ws;
    size_t cur = 0;
    auto allocB = [&](size_t bytes) { char* p = base + cur; cur = (cur + bytes + 255) & ~(size_t)255; return p; };
    auto allocF = [&](size_t n) { return (float*)allocB(n * 4); };
    auto allocH = [&](size_t n) { return (ushort*)allocB(n * 2); };

    // fp32
    float* h     = allocF((size_t)kMtok * kD);
    float* xz    = allocF((size_t)kMtok * 2 * kDi);
    float* xc    = allocF((size_t)kMtok * kDi);
    float* dblb  = allocF((size_t)kMtok * 128);
    float* dlt   = allocF((size_t)kMtok * kDi);
    float* st    = allocF((size_t)kNL * kB * kDi * kN);
    float* x768  = allocF((size_t)kMref * kD);
    float* qkvB  = allocF((size_t)kMref * 3 * kD);
    float* d1536 = allocF((size_t)kMref * kDi);
    // bf16 activations
    ushort* xin_bf  = allocH((size_t)kMtok * kD);
    ushort* xc_bf   = allocH((size_t)kMtok * kDi);
    ushort* dtin_bf = allocH((size_t)kMtok * 64);
    ushort* yb_bf   = allocH((size_t)kMtok * kDi);
    ushort* dDi_bf  = allocH((size_t)128 * kDi);
    ushort* tb_bf   = allocH((size_t)128 * kD);
    ushort* o768_bf = allocH((size_t)128 * kD);
    ushort* f3_bf   = allocH((size_t)128 * 4 * kD);
    ushort* x768_bf = allocH((size_t)128 * kD);
    // bf16 weights
    ushort* ipw_bf  = allocH((size_t)2 * kDi * kD);        // per-layer staging
    ushort* opw_bf  = allocH((size_t)kD * kDi);            // per-layer staging
    ushort* xpw_bf  = allocH((size_t)kNL * 128 * kDi);     // padded N
    ushort* dpw_bf  = allocH((size_t)kNL * kDi * 64);      // padded K
    ushort* powp_bf = allocH((size_t)kD * kDi);
    ushort* qkvw_bf = allocH((size_t)3 * kD * kD);
    ushort* aow_bf  = allocH((size_t)kD * kD);
    ushort* ff1w_bf = allocH((size_t)4 * kD * kD);
    ushort* ff2w_bf = allocH((size_t)kD * 4 * kD);
    ushort* piw_bf  = allocH((size_t)kDi * kD);
    ushort* emb_bf  = allocH((size_t)kVp * kD);
    if (cur > ws_size) return;  // workspace too small -> loud failure

    auto cvt = [&](const float* s, ushort* d, size_t n) {
        cvt_kernel<<<dim3((unsigned)((n / 4 + 255) / 256)), dim3(256), 0, stream>>>(s, d, (int)n);
    };

    hipMemsetAsync(st, 0, sizeof(float) * (size_t)kNL * kB * kDi * kN, stream);

    // ---- upfront weight conversions ----
    cvt_xpw_kernel<<<dim3(2880), dim3(256), 0, stream>>>(xpw, xpw_bf);
    cvt_dpw_kernel<<<dim3(9216), dim3(256), 0, stream>>>(dpw, dpw_bf);
    cvt(powp, powp_bf, (size_t)kD * kDi);
    cvt(qkvw, qkvw_bf, (size_t)3 * kD * kD);
    cvt(aow,  aow_bf,  (size_t)kD * kD);
    cvt(ff1w, ff1w_bf, (size_t)4 * kD * kD);
    cvt(ff2w, ff2w_bf, (size_t)kD * 4 * kD);
    cvt(piwp, piw_bf,  (size_t)kDi * kD);
    cvt(embed, emb_bf, (size_t)kV * kD);   // pad rows stay garbage (finite) -> unstored C cols

    for (int pass = 0; pass < 2; ++pass) {
        const int* ids = pass ? a_ids : q_ids;
        const int* msk = pass ? a_msk : q_msk;

        embed_kernel<<<dim3(kMtok * kD / 256), dim3(256), 0, stream>>>(ids, msk, embed, h);

        for (int l = 0; l < kNL; ++l) {
            rms_kernel<<<dim3(kMtok), dim3(256), 0, stream>>>(h, norm_w + (size_t)l * kD, xin_bf);
            cvt(ipw + (size_t)l * 2 * kDi * kD, ipw_bf, (size_t)2 * kDi * kD);
            gemm<0, 0, 0, 0>(xin_bf, kD, ipw_bf, kD, xz, 2 * kDi, nullptr, 0,
                             nullptr, kMtok, 2 * kDi, kD, stream);
            conv_kernel<<<dim3(kMtok * kDi / 256), dim3(256), 0, stream>>>(
                xz, cw + (size_t)l * kDi * kK, cb + (size_t)l * kDi, xc, xc_bf);
            gemm<0, 0, 0, 0>(xc_bf, kDi, xpw_bf + (size_t)l * 128 * kDi, kDi, dblb, 128, nullptr, 0,
                             nullptr, kMtok, 80, kDi, stream);
            dtpad_kernel<<<dim3(kMtok * 64 / 256), dim3(256), 0, stream>>>(dblb, dtin_bf);
            gemm<1, 1, 0, 0>(dtin_bf, 64, dpw_bf + (size_t)l * kDi * 64, 64, dlt, kDi, nullptr, 0,
                             dpb + (size_t)l * kDi, kMtok, kDi, 64, stream);
            scan_kernel<<<dim3(kB * kDi * kN / 256), dim3(256), 0, stream>>>(
                dlt, xc, xz, dblb, alog + (size_t)l * kDi * kN, dpp + (size_t)l * kDi,
                st + (size_t)l * kB * kDi * kN, yb_bf);
            cvt(opw + (size_t)l * kD * kDi, opw_bf, (size_t)kD * kDi);
            gemm<0, 0, 1, 0>(yb_bf, kDi, opw_bf, kDi, h, kD, nullptr, 0,
                             nullptr, kMtok, kD, kDi, stream);
        }

        if (pass == 0) {
            for (int it = 0; it < 12; ++it) {
                contract_kernel<<<dim3(kMref * kDi / 256), dim3(256), 0, stream>>>(st, Cwp, dDi_bf);
                gemm<0, 0, 0, 0>(dDi_bf, kDi, powp_bf, kDi, x768, kD, nullptr, 0,
                                 nullptr, kMref, kD, kDi, stream);
                ln_kernel<<<dim3(kMref), dim3(256), 0, stream>>>(x768, ln1w, ln1b, tb_bf);
                gemm<1, 0, 0, 0>(tb_bf, kD, qkvw_bf, kD, qkvB, 3 * kD, nullptr, 0,
                                 qkvbi, kMref, 3 * kD, kD, stream);
                attn_kernel<<<dim3(kB * kNH), dim3(32), 0, stream>>>(qkvB, o768_bf);
                gemm<1, 0, 1, 0>(o768_bf, kD, aow_bf, kD, x768, kD, nullptr, 0,
                                 aob, kMref, kD, kD, stream);
                ln_kernel<<<dim3(kMref), dim3(256), 0, stream>>>(x768, ln2w, ln2b, tb_bf);
                gemm<1, 2, 0, 2>(tb_bf, kD, ff1w_bf, kD, nullptr, 0, f3_bf, 4 * kD,
                                 ff1b, kMref, 4 * kD, kD, stream);
                gemm<1, 0, 1, 1>(f3_bf, 4 * kD, ff2w_bf, 4 * kD, x768, kD, x768_bf, kD,
                                 ff2b, kMref, kD, 4 * kD, stream);
                gemm<0, 0, 0, 0>(x768_bf, kD, piw_bf, kD, d1536, kDi, nullptr, 0,
                                 nullptr, kMref, kDi, kD, stream);
                update_kernel<<<dim3(kMref * kDi / 256), dim3(256), 0, stream>>>(d1536, Bwp, st);
            }
        } else {
            rms_kernel<<<dim3(kMtok), dim3(256), 0, stream>>>(h, norm_f, xin_bf);
            gemm<0, 0, 0, 0>(xin_bf, kD, emb_bf, kD, (float*)d_out, kV, nullptr, 0,
                             nullptr, kMtok, kV, kD, stream);
        }
    }
}

// Round 3
// 14088.438 us; speedup vs baseline: 3.6554x; 1.5338x over previous
//
#include <hip/hip_runtime.h>
#include <math.h>

namespace {

constexpr int kNL = 24, kD = 768, kDi = 1536, kN = 16, kR = 48, kK = 4, kV = 50280, kNH = 12;
constexpr int kB = 4, kS = 256;
constexpr int kMtok = kB * kS;   // 1024 token rows
constexpr int kMref = kB * kNL;  // 96 refine rows
constexpr int kVp = 50304;       // kV padded to 128

using bf16x8 = __attribute__((ext_vector_type(8))) short;
using f32x4  = __attribute__((ext_vector_type(4))) float;

__device__ __forceinline__ float siluf(float x) { return x / (1.f + __expf(-x)); }

__device__ __forceinline__ ushort f2b(float f) {
    union { float f; unsigned u; } v; v.f = f;
    unsigned u = v.u;
    unsigned r = (u + 0x7FFFu + ((u >> 16) & 1u)) >> 16;
    return (ushort)r;
}

#define GLOAD_LDS(g, l) \
    __builtin_amdgcn_global_load_lds((const __attribute__((address_space(1))) void*)(g), \
                                     (__attribute__((address_space(3))) void*)(l), 16, 0, 0)

// ---------------- bf16 MFMA GEMM: C[M,N] = A[M,K] @ B[N,K]^T ----------------
// Double-buffered LDS, prefetch-next-tile-then-compute (2-phase).
// ACT: 0 none, 1 softplus, 2 gelu(exact).
// OUTMODE: 0 fp32 C; 1 fp32 C + bf16 Cbf; 2 bf16 Cbf only; 3 x_proj special
//          (gn<48 -> bf16 dt-in (Cbf, ld 64) with zeroed cols 48..63; gn in
//          [48,80) -> fp32 B/C buffer (C, ld 32)).
template <int BM, int BN, int BIAS, int ACT, int RES, int OUTMODE>
__global__ __launch_bounds__(256, (BM == 64 ? 4 : 2)) void gemm_bf16(
    const ushort* __restrict__ A, int lda,
    const ushort* __restrict__ B, int ldb,
    float* __restrict__ C, int ldc,
    ushort* __restrict__ Cbf, int ldcb,
    const float* __restrict__ bias,
    int M, int N, int K)
{
    constexpr int ACH = BM / 64;   // A GLOAD chunks per wave
    constexpr int BCH = BN / 64;
    constexpr int MI  = BM / 32;   // fragment rows per wave
    constexpr int NJ  = BN / 32;

    __shared__ ushort As[2][BM * 32];
    __shared__ ushort Bs[2][BN * 32];

    const int tid  = threadIdx.x;
    const int lane = tid & 63;
    const int wave = tid >> 6;
    const int m0 = blockIdx.y * BM;
    const int n0 = blockIdx.x * BN;
    const int wr = (wave >> 1) * (BM / 2);
    const int wc = (wave & 1) * (BN / 2);

    f32x4 acc[MI][NJ];
#pragma unroll
    for (int i = 0; i < MI; ++i)
#pragma unroll
        for (int j = 0; j < NJ; ++j) acc[i][j] = f32x4{0.f, 0.f, 0.f, 0.f};

    // staging pointers: chunk c = wave*CH+g covers rows [c*16, c*16+16)
    const int r4 = lane >> 2;
    const int c8 = (lane & 3) * 8;
    const ushort* gA[ACH];
    const ushort* gB[BCH];
#pragma unroll
    for (int g = 0; g < ACH; ++g)
        gA[g] = A + (size_t)(m0 + (wave * ACH + g) * 16 + r4) * lda + c8;
#pragma unroll
    for (int g = 0; g < BCH; ++g)
        gB[g] = B + (size_t)(n0 + (wave * BCH + g) * 16 + r4) * ldb + c8;

    const int frow = lane & 15;
    const int fk   = (lane >> 4) * 8;
    const int nt = K >> 5;

    // prologue: stage tile 0 into buffer 0
#pragma unroll
    for (int g = 0; g < ACH; ++g) GLOAD_LDS(gA[g], &As[0][(wave * ACH + g) * 512]);
#pragma unroll
    for (int g = 0; g < BCH; ++g) GLOAD_LDS(gB[g], &Bs[0][(wave * BCH + g) * 512]);
    __syncthreads();

    int cur = 0;
    for (int t = 0; t < nt; ++t) {
        if (t + 1 < nt) {
            const int off = (t + 1) * 32;
#pragma unroll
            for (int g = 0; g < ACH; ++g) GLOAD_LDS(gA[g] + off, &As[cur ^ 1][(wave * ACH + g) * 512]);
#pragma unroll
            for (int g = 0; g < BCH; ++g) GLOAD_LDS(gB[g] + off, &Bs[cur ^ 1][(wave * BCH + g) * 512]);
        }
        bf16x8 fa[MI], fb[NJ];
#pragma unroll
        for (int i = 0; i < MI; ++i) fa[i] = *(const bf16x8*)&As[cur][(wr + i * 16 + frow) * 32 + fk];
#pragma unroll
        for (int j = 0; j < NJ; ++j) fb[j] = *(const bf16x8*)&Bs[cur][(wc + j * 16 + frow) * 32 + fk];
#pragma unroll
        for (int i = 0; i < MI; ++i)
#pragma unroll
            for (int j = 0; j < NJ; ++j)
                acc[i][j] = __builtin_amdgcn_mfma_f32_16x16x32_bf16(fa[i], fb[j], acc[i][j], 0, 0, 0);
        __syncthreads();
        cur ^= 1;
    }

    // epilogue: C/D layout col = lane&15, row = (lane>>4)*4 + q
    const int ccol = lane & 15;
    const int crow = (lane >> 4) * 4;
#pragma unroll
    for (int i = 0; i < MI; ++i) {
#pragma unroll
        for (int j = 0; j < NJ; ++j) {
            int gn = n0 + wc + j * 16 + ccol;
            if (gn >= N) continue;
            float bv = BIAS ? bias[gn] : 0.f;
#pragma unroll
            for (int q = 0; q < 4; ++q) {
                int gm = m0 + wr + i * 16 + crow + q;
                if (gm >= M) continue;
                float v = acc[i][j][q] + bv;
                if (ACT == 1) v = fmaxf(v, 0.f) + log1pf(expf(-fabsf(v)));
                if (ACT == 2) v = 0.5f * v * (1.f + erff(v * 0.70710678118654752f));
                if (OUTMODE == 3) {
                    if (gn < 48) Cbf[(size_t)gm * 64 + gn] = f2b(v);
                    else if (gn < 64) { Cbf[(size_t)gm * 64 + gn] = 0; C[(size_t)gm * 32 + (gn - 48)] = v; }
                    else if (gn < 80) C[(size_t)gm * 32 + (gn - 48)] = v;
                } else {
                    size_t ci = (size_t)gm * ldc + gn;
                    if (RES) v += C[ci];
                    if (OUTMODE != 2) C[ci] = v;
                    if (OUTMODE == 1 || OUTMODE == 2) Cbf[(size_t)gm * ldcb + gn] = f2b(v);
                }
            }
        }
    }
}

template <int BM, int BN, int BIAS, int ACT, int RES, int OUTMODE>
static void gemm(const ushort* A, int lda, const ushort* B, int ldb,
                 float* C, int ldc, ushort* Cb, int ldcb,
                 const float* bias, int M, int N, int K, hipStream_t s)
{
    dim3 g((N + BN - 1) / BN, (M + BM - 1) / BM);
    gemm_bf16<BM, BN, BIAS, ACT, RES, OUTMODE><<<g, dim3(256), 0, s>>>(A, lda, B, ldb, C, ldc, Cb, ldcb, bias, M, N, K);
}

// ---------------- conversions ----------------
__global__ void cvt_kernel(const float* __restrict__ src, ushort* __restrict__ dst, int n) {
    int i = (blockIdx.x * 256 + threadIdx.x) * 4;
    if (i >= n) return;
    float4 v = *(const float4*)(src + i);
    ushort4 o; o.x = f2b(v.x); o.y = f2b(v.y); o.z = f2b(v.z); o.w = f2b(v.w);
    *(ushort4*)(dst + i) = o;
}

// xpw [24][80][1536] -> padded [24][128][1536]
__global__ void cvt_xpw_kernel(const float* __restrict__ src, ushort* __restrict__ dst) {
    int i = (blockIdx.x * 256 + threadIdx.x) * 4;
    if (i >= 24 * 80 * 1536) return;
    int l = i / (80 * 1536), r = i - l * (80 * 1536);
    int row = r / 1536, col = r - row * 1536;
    float4 v = *(const float4*)(src + i);
    ushort4 o; o.x = f2b(v.x); o.y = f2b(v.y); o.z = f2b(v.z); o.w = f2b(v.w);
    *(ushort4*)(dst + ((size_t)(l * 128 + row)) * 1536 + col) = o;
}

// dpw [24][1536][48] -> padded [24][1536][64] (K-pad zero)
__global__ void cvt_dpw_kernel(const float* __restrict__ src, ushort* __restrict__ dst) {
    int i = blockIdx.x * 256 + threadIdx.x;
    if (i >= 24 * 1536 * 64) return;
    int col = i & 63, row = i >> 6;
    dst[i] = (col < 48) ? f2b(src[(size_t)row * 48 + col]) : (ushort)0;
}

// ---------------- embedding ----------------
__global__ void embed_kernel(const int* __restrict__ ids, const int* __restrict__ msk,
                             const float* __restrict__ embed, float* __restrict__ h)
{
    int i = blockIdx.x * 256 + threadIdx.x;
    int row = i / kD, col = i - row * kD;
    h[i] = embed[(size_t)ids[row] * kD + col] * (float)msk[row];
}

// ---------------- RMSNorm -> bf16 ----------------
__global__ __launch_bounds__(256) void rms_kernel(const float* __restrict__ x,
                                                  const float* __restrict__ w,
                                                  ushort* __restrict__ out)
{
    __shared__ float red[256];
    int row = blockIdx.x, tid = threadIdx.x;
    const float* xr = x + (size_t)row * kD;
    float s = 0.f;
    for (int j = tid; j < kD; j += 256) { float v = xr[j]; s += v * v; }
    red[tid] = s; __syncthreads();
    for (int o = 128; o > 0; o >>= 1) { if (tid < o) red[tid] += red[tid + o]; __syncthreads(); }
    float rs = rsqrtf(red[0] / (float)kD + 1e-5f);
    for (int j = tid; j < kD; j += 256) out[(size_t)row * kD + j] = f2b(xr[j] * rs * w[j]);
}

// ---------------- LayerNorm -> bf16 ----------------
__global__ __launch_bounds__(256) void ln_kernel(const float* __restrict__ x,
                                                 const float* __restrict__ w,
                                                 const float* __restrict__ b,
                                                 ushort* __restrict__ out)
{
    __shared__ float r1[256], r2[256];
    int row = blockIdx.x, tid = threadIdx.x;
    const float* xr = x + (size_t)row * kD;
    float s = 0.f, s2 = 0.f;
    for (int j = tid; j < kD; j += 256) { float v = xr[j]; s += v; s2 += v * v; }
    r1[tid] = s; r2[tid] = s2; __syncthreads();
    for (int o = 128; o > 0; o >>= 1) {
        if (tid < o) { r1[tid] += r1[tid + o]; r2[tid] += r2[tid + o]; }
        __syncthreads();
    }
    float mean = r1[0] / (float)kD;
    float var = r2[0] / (float)kD - mean * mean;
    float rs = rsqrtf(var + 1e-5f);
    for (int j = tid; j < kD; j += 256)
        out[(size_t)row * kD + j] = f2b((xr[j] - mean) * rs * w[j] + b[j]);
}

// ---------------- causal conv (K=4) + bias + silu ----------
__global__ void conv_kernel(const float* __restrict__ xz, const float* __restrict__ cw,
                            const float* __restrict__ cb, float* __restrict__ xc,
                            ushort* __restrict__ xc_bf)
{
    int i = blockIdx.x * 256 + threadIdx.x;   // kMtok * kDi
    int bt = i / kDi, d = i - bt * kDi;
    int b = bt / kS, t = bt - b * kS;
    float s = cb[d];
#pragma unroll
    for (int k = 0; k < kK; ++k) {
        int tt = t - (kK - 1) + k;
        if (tt >= 0) s += xz[(size_t)(b * kS + tt) * (2 * kDi) + d] * cw[d * kK + k];
    }
    float v = siluf(s);
    xc[i] = v;
    xc_bf[i] = f2b(v);
}

// ---------------- selective scan + gating (register-prefetched) -----------
__global__ __launch_bounds__(256) void scan_kernel(
    const float* __restrict__ dlt, const float* __restrict__ xc,
    const float* __restrict__ xz, const float* __restrict__ bc,
    const float* __restrict__ alog, const float* __restrict__ dp,
    float* __restrict__ states, ushort* __restrict__ y)
{
    int gid = blockIdx.x * 256 + threadIdx.x;    // kB*kDi*kN threads
    int n = gid & 15;
    int d = (gid >> 4) % kDi;
    int b = gid / (kDi * kN);
    float Areg = -__expf(alog[d * kN + n]);
    float dpv = dp[d];
    size_t sidx = (size_t)(b * kDi + d) * kN + n;
    float hs = states[sidx];
    size_t bt0 = (size_t)b * kS;
    float dv = dlt[bt0 * kDi + d];
    float xv = xc[bt0 * kDi + d];
    float Bv = bc[bt0 * 32 + n];
    float Cv = bc[bt0 * 32 + 16 + n];
    for (int t = 0; t < kS; ++t) {
        float dvn = 0.f, xvn = 0.f, Bvn = 0.f, Cvn = 0.f;
        if (t + 1 < kS) {
            size_t bt1 = bt0 + t + 1;
            dvn = dlt[bt1 * kDi + d];
            xvn = xc[bt1 * kDi + d];
            Bvn = bc[bt1 * 32 + n];
            Cvn = bc[bt1 * 32 + 16 + n];
        }
        hs = __expf(dv * Areg) * hs + (dv * xv) * Bv;
        float p = hs * Cv;
        p += __shfl_xor(p, 1, 16);
        p += __shfl_xor(p, 2, 16);
        p += __shfl_xor(p, 4, 16);
        p += __shfl_xor(p, 8, 16);
        if (n == 0) {
            size_t bt = bt0 + t;
            float zv = xz[bt * (2 * kDi) + kDi + d];
            y[bt * kDi + d] = f2b((p + xv * dpv) * siluf(zv));
        }
        dv = dvn; xv = xvn; Bv = Bvn; Cv = Cvn;
    }
    states[sidx] = hs;
}

// ---------------- refine: d = states . C_w -> bf16 [row, di] --------------
__global__ void contract_kernel(const float* __restrict__ st, const float* __restrict__ Cw,
                                ushort* __restrict__ dDi)
{
    int i = blockIdx.x * 256 + threadIdx.x;      // kMref * kDi
    int row = i / kDi, di = i - row * kDi;
    int b = row / kNL, s = row - b * kNL;
    const float* sp = st + ((size_t)(s * kB + b) * kDi + di) * kN;
    float acc = 0.f;
#pragma unroll
    for (int nn = 0; nn < kN; ++nn) acc += sp[nn] * Cw[nn];
    dDi[i] = f2b(acc);
}

// ---------------- refine: states += d1536 * B_w --------------------------
__global__ void update_kernel(const float* __restrict__ d1536, const float* __restrict__ Bw,
                              float* __restrict__ st)
{
    int i = blockIdx.x * 256 + threadIdx.x;      // kMref * kDi
    int row = i / kDi, di = i - row * kDi;
    int b = row / kNL, s = row - b * kNL;
    float dv = d1536[i];
    float* sp = st + ((size_t)(s * kB + b) * kDi + di) * kN;
#pragma unroll
    for (int nn = 0; nn < kN; ++nn) sp[nn] += dv * Bw[nn];
}

// ---------------- tiny attention (B=4, S=24, 12 heads, hd=64) -> bf16 -----
__global__ __launch_bounds__(32) void attn_kernel(const float* __restrict__ qkv,
                                                  ushort* __restrict__ o)
{
    int b = blockIdx.x / kNH;
    int hh = blockIdx.x - b * kNH;
    int sq = threadIdx.x;
    if (sq >= kNL) return;
    const float* qrow = qkv + (size_t)(b * kNL + sq) * (3 * kD) + hh * 64;
    float q[64];
#pragma unroll
    for (int e = 0; e < 64; ++e) q[e] = qrow[e];
    float sc[kNL];
    float mx = -1e30f;
    for (int sk = 0; sk < kNL; ++sk) {
        const float* krow = qkv + (size_t)(b * kNL + sk) * (3 * kD) + kD + hh * 64;
        float dt = 0.f;
#pragma unroll
        for (int e = 0; e < 64; ++e) dt += q[e] * krow[e];
        dt *= 0.125f;
        sc[sk] = dt;
        mx = fmaxf(mx, dt);
    }
    float sum = 0.f;
    for (int sk = 0; sk < kNL; ++sk) { sc[sk] = expf(sc[sk] - mx); sum += sc[sk]; }
    float inv = 1.f / sum;
    float out[64];
#pragma unroll
    for (int e = 0; e < 64; ++e) out[e] = 0.f;
    for (int sk = 0; sk < kNL; ++sk) {
        float wgt = sc[sk] * inv;
        const float* vrow = qkv + (size_t)(b * kNL + sk) * (3 * kD) + 2 * kD + hh * 64;
#pragma unroll
        for (int e = 0; e < 64; ++e) out[e] += wgt * vrow[e];
    }
    ushort* orow = o + (size_t)(b * kNL + sq) * kD + hh * 64;
#pragma unroll
    for (int e = 0; e < 64; ++e) orow[e] = f2b(out[e]);
}

} // namespace

extern "C" void kernel_launch(void* const* d_in, const int* in_sizes, int n_in,
                              void* d_out, int out_size, void* d_ws, size_t ws_size,
                              hipStream_t stream)
{
    const int*   q_ids  = (const int*)d_in[0];
    const int*   q_msk  = (const int*)d_in[1];
    const int*   a_ids  = (const int*)d_in[2];
    const int*   a_msk  = (const int*)d_in[3];
    const float* embed  = (const float*)d_in[4];
    const float* norm_w = (const float*)d_in[5];
    const float* ipw    = (const float*)d_in[6];
    const float* cw     = (const float*)d_in[7];
    const float* cb     = (const float*)d_in[8];
    const float* xpw    = (const float*)d_in[9];
    const float* dpw    = (const float*)d_in[10];
    const float* dpb    = (const float*)d_in[11];
    const float* alog   = (const float*)d_in[12];
    const float* dpp    = (const float*)d_in[13];
    const float* opw    = (const float*)d_in[14];
    const float* norm_f = (const float*)d_in[15];
    const float* ln1w   = (const float*)d_in[16];
    const float* ln1b   = (const float*)d_in[17];
    const float* qkvw   = (const float*)d_in[18];
    const float* qkvbi  = (const float*)d_in[19];
    const float* aow    = (const float*)d_in[20];
    const float* aob    = (const float*)d_in[21];
    const float* ln2w   = (const float*)d_in[22];
    const float* ln2b   = (const float*)d_in[23];
    const float* ff1w   = (const float*)d_in[24];
    const float* ff1b   = (const float*)d_in[25];
    const float* ff2w   = (const float*)d_in[26];
    const float* ff2b   = (const float*)d_in[27];
    const float* Cwp    = (const float*)d_in[28];
    const float* powp   = (const float*)d_in[29];
    const float* Bwp    = (const float*)d_in[30];
    const float* piwp   = (const float*)d_in[31];

    // ---- workspace arena (byte cursor, 256B aligned) ----
    char* base = (char*)d_ws;
    size_t cur = 0;
    auto allocB = [&](size_t bytes) { char* p = base + cur; cur = (cur + bytes + 255) & ~(size_t)255; return p; };
    auto allocF = [&](size_t n) { return (float*)allocB(n * 4); };
    auto allocH = [&](size_t n) { return (ushort*)allocB(n * 2); };

    // fp32
    float* h     = allocF((size_t)kMtok * kD);
    float* xz    = allocF((size_t)kMtok * 2 * kDi);
    float* xc    = allocF((size_t)kMtok * kDi);
    float* bcb   = allocF((size_t)kMtok * 32);
    float* dlt   = allocF((size_t)kMtok * kDi);
    float* st    = allocF((size_t)kNL * kB * kDi * kN);
    float* x768  = allocF((size_t)kMref * kD);
    float* qkvB  = allocF((size_t)kMref * 3 * kD);
    float* d1536 = allocF((size_t)kMref * kDi);
    // bf16 activations
    ushort* xin_bf  = allocH((size_t)kMtok * kD);
    ushort* xc_bf   = allocH((size_t)kMtok * kDi);
    ushort* dtin_bf = allocH((size_t)kMtok * 64);
    ushort* yb_bf   = allocH((size_t)kMtok * kDi);
    ushort* dDi_bf  = allocH((size_t)128 * kDi);
    ushort* tb_bf   = allocH((size_t)128 * kD);
    ushort* o768_bf = allocH((size_t)128 * kD);
    ushort* f3_bf   = allocH((size_t)128 * 4 * kD);
    ushort* x768_bf = allocH((size_t)128 * kD);
    // bf16 weights (always resident)
    ushort* xpw_bf  = allocH((size_t)kNL * 128 * kDi);
    ushort* dpw_bf  = allocH((size_t)kNL * kDi * 64);
    ushort* powp_bf = allocH((size_t)kD * kDi);
    ushort* qkvw_bf = allocH((size_t)3 * kD * kD);
    ushort* aow_bf  = allocH((size_t)kD * kD);
    ushort* ff1w_bf = allocH((size_t)4 * kD * kD);
    ushort* ff2w_bf = allocH((size_t)kD * 4 * kD);
    ushort* piw_bf  = allocH((size_t)kDi * kD);
    ushort* emb_bf  = allocH((size_t)kVp * kD);

    // try full upfront conversion of ipw/opw; fallback to per-layer staging
    size_t base_end = cur;
    ushort* ipw_all = allocH((size_t)kNL * 2 * kDi * kD);
    ushort* opw_all = allocH((size_t)kNL * kD * kDi);
    bool full = (cur <= ws_size);
    ushort* ipw_stg = nullptr;
    ushort* opw_stg = nullptr;
    if (!full) {
        cur = base_end;
        ipw_stg = allocH((size_t)2 * kDi * kD);
        opw_stg = allocH((size_t)kD * kDi);
        if (cur > ws_size) return;  // even base does not fit -> loud failure
    }

    auto cvt = [&](const float* s, ushort* d, size_t n) {
        cvt_kernel<<<dim3((unsigned)((n / 4 + 255) / 256)), dim3(256), 0, stream>>>(s, d, (int)n);
    };

    hipMemsetAsync(st, 0, sizeof(float) * (size_t)kNL * kB * kDi * kN, stream);

    // ---- upfront weight conversions ----
    cvt_xpw_kernel<<<dim3(2880), dim3(256), 0, stream>>>(xpw, xpw_bf);
    cvt_dpw_kernel<<<dim3(9216), dim3(256), 0, stream>>>(dpw, dpw_bf);
    cvt(powp, powp_bf, (size_t)kD * kDi);
    cvt(qkvw, qkvw_bf, (size_t)3 * kD * kD);
    cvt(aow,  aow_bf,  (size_t)kD * kD);
    cvt(ff1w, ff1w_bf, (size_t)4 * kD * kD);
    cvt(ff2w, ff2w_bf, (size_t)kD * 4 * kD);
    cvt(piwp, piw_bf,  (size_t)kDi * kD);
    cvt(embed, emb_bf, (size_t)kV * kD);
    if (full) {
        cvt(ipw, ipw_all, (size_t)kNL * 2 * kDi * kD);
        cvt(opw, opw_all, (size_t)kNL * kD * kDi);
    }

    for (int pass = 0; pass < 2; ++pass) {
        const int* ids = pass ? a_ids : q_ids;
        const int* msk = pass ? a_msk : q_msk;

        embed_kernel<<<dim3(kMtok * kD / 256), dim3(256), 0, stream>>>(ids, msk, embed, h);

        for (int l = 0; l < kNL; ++l) {
            const ushort* ipw_l;
            const ushort* opw_l;
            if (full) {
                ipw_l = ipw_all + (size_t)l * 2 * kDi * kD;
                opw_l = opw_all + (size_t)l * kD * kDi;
            } else {
                cvt(ipw + (size_t)l * 2 * kDi * kD, ipw_stg, (size_t)2 * kDi * kD);
                cvt(opw + (size_t)l * kD * kDi, opw_stg, (size_t)kD * kDi);
                ipw_l = ipw_stg;
                opw_l = opw_stg;
            }
            rms_kernel<<<dim3(kMtok), dim3(256), 0, stream>>>(h, norm_w + (size_t)l * kD, xin_bf);
            gemm<64, 64, 0, 0, 0, 0>(xin_bf, kD, ipw_l, kD, xz, 2 * kDi, nullptr, 0,
                                     nullptr, kMtok, 2 * kDi, kD, stream);
            conv_kernel<<<dim3(kMtok * kDi / 256), dim3(256), 0, stream>>>(
                xz, cw + (size_t)l * kDi * kK, cb + (size_t)l * kDi, xc, xc_bf);
            gemm<64, 64, 0, 0, 0, 3>(xc_bf, kDi, xpw_bf + (size_t)l * 128 * kDi, kDi,
                                     bcb, 0, dtin_bf, 0, nullptr, kMtok, 128, kDi, stream);
            gemm<64, 64, 1, 1, 0, 0>(dtin_bf, 64, dpw_bf + (size_t)l * kDi * 64, 64, dlt, kDi,
                                     nullptr, 0, dpb + (size_t)l * kDi, kMtok, kDi, 64, stream);
            scan_kernel<<<dim3(kB * kDi * kN / 256), dim3(256), 0, stream>>>(
                dlt, xc, xz, bcb, alog + (size_t)l * kDi * kN, dpp + (size_t)l * kDi,
                st + (size_t)l * kB * kDi * kN, yb_bf);
            gemm<64, 64, 0, 0, 1, 0>(yb_bf, kDi, opw_l, kDi, h, kD, nullptr, 0,
                                     nullptr, kMtok, kD, kDi, stream);
        }

        if (pass == 0) {
            for (int it = 0; it < 12; ++it) {
                contract_kernel<<<dim3(kMref * kDi / 256), dim3(256), 0, stream>>>(st, Cwp, dDi_bf);
                gemm<64, 64, 0, 0, 0, 0>(dDi_bf, kDi, powp_bf, kDi, x768, kD, nullptr, 0,
                                         nullptr, kMref, kD, kDi, stream);
                ln_kernel<<<dim3(kMref), dim3(256), 0, stream>>>(x768, ln1w, ln1b, tb_bf);
                gemm<64, 64, 1, 0, 0, 0>(tb_bf, kD, qkvw_bf, kD, qkvB, 3 * kD, nullptr, 0,
                                         qkvbi, kMref, 3 * kD, kD, stream);
                attn_kernel<<<dim3(kB * kNH), dim3(32), 0, stream>>>(qkvB, o768_bf);
                gemm<64, 64, 1, 0, 1, 0>(o768_bf, kD, aow_bf, kD, x768, kD, nullptr, 0,
                                         aob, kMref, kD, kD, stream);
                ln_kernel<<<dim3(kMref), dim3(256), 0, stream>>>(x768, ln2w, ln2b, tb_bf);
                gemm<64, 64, 1, 2, 0, 2>(tb_bf, kD, ff1w_bf, kD, nullptr, 0, f3_bf, 4 * kD,
                                         ff1b, kMref, 4 * kD, kD, stream);
                gemm<64, 64, 1, 0, 1, 1>(f3_bf, 4 * kD, ff2w_bf, 4 * kD, x768, kD, x768_bf, kD,
                                         ff2b, kMref, kD, 4 * kD, stream);
                gemm<64, 64, 0, 0, 0, 0>(x768_bf, kD, piw_bf, kD, d1536, kDi, nullptr, 0,
                                         nullptr, kMref, kDi, kD, stream);
                update_kernel<<<dim3(kMref * kDi / 256), dim3(256), 0, stream>>>(d1536, Bwp, st);
            }
        } else {
            rms_kernel<<<dim3(kMtok), dim3(256), 0, stream>>>(h, norm_f, xin_bf);
            gemm<128, 128, 0, 0, 0, 0>(xin_bf, kD, emb_bf, kD, (float*)d_out, kV, nullptr, 0,
                                       nullptr, kMtok, kV, kD, stream);
        }
    }
}